// Round 5
// baseline (521.916 us; speedup 1.0000x reference)
//
#include <hip/hip_runtime.h>

typedef unsigned short u16;
typedef __attribute__((ext_vector_type(8))) short bf16x8;
typedef __attribute__((ext_vector_type(4))) float f32x4;
typedef __attribute__((ext_vector_type(4))) unsigned int u32x4;

__device__ __forceinline__ u16 f2bf(float f) {
  unsigned u = __builtin_bit_cast(unsigned, f);
  u += 0x7fffu + ((u >> 16) & 1u);
  return (u16)(u >> 16);
}

__device__ __forceinline__ unsigned pkbf(float lo, float hi) {
  unsigned r;
  asm("v_cvt_pk_bf16_f32 %0, %1, %2" : "=v"(r) : "v"(lo), "v"(hi));
  return r;
}

__device__ __forceinline__ void gll16(const void* g, void* l) {
  __builtin_amdgcn_global_load_lds((const __attribute__((address_space(1))) void*)g,
                                   (__attribute__((address_space(3))) void*)l, 16, 0, 0);
}

// ---------------- bias concat: bc[1280] = [bq | bk | bv] ----------------
__global__ void build_bias_k(const float* __restrict__ bq, const float* __restrict__ bk,
                             const float* __restrict__ bv, float* __restrict__ bc) {
  int i = blockIdx.x * 256 + threadIdx.x;
  if (i < 1280) bc[i] = (i < 128) ? bq[i] : ((i < 256) ? bk[i - 128] : bv[i - 256]);
}

// ------- weight transpose: wt[n][f] bf16, n in [0,1280), f in [0,1024) -------
__global__ void transpose_w_k(const float* __restrict__ Wq, const float* __restrict__ Wk,
                              const float* __restrict__ Wv, u16* __restrict__ wt) {
  __shared__ float tile[64][65];
  const int n0 = blockIdx.x * 64;
  const int f0 = blockIdx.y * 64;
  const int t = threadIdx.x;
  const float* src; int ld, coff;
  if (n0 < 128)      { src = Wq; ld = 128;  coff = n0; }
  else if (n0 < 256) { src = Wk; ld = 128;  coff = n0 - 128; }
  else               { src = Wv; ld = 1024; coff = n0 - 256; }
  const int r = t >> 4, c4 = (t & 15) * 4;
  #pragma unroll
  for (int i = 0; i < 4; ++i) {
    float4 v = *(const float4*)(src + (size_t)(f0 + r + 16 * i) * ld + coff + c4);
    tile[r + 16 * i][c4 + 0] = v.x;
    tile[r + 16 * i][c4 + 1] = v.y;
    tile[r + 16 * i][c4 + 2] = v.z;
    tile[r + 16 * i][c4 + 3] = v.w;
  }
  __syncthreads();
  #pragma unroll
  for (int i = 0; i < 4; ++i) {
    const int nr = r + 16 * i;
    ushort4 h;
    h.x = f2bf(tile[c4 + 0][nr]);
    h.y = f2bf(tile[c4 + 1][nr]);
    h.z = f2bf(tile[c4 + 2][nr]);
    h.w = f2bf(tile[c4 + 3][nr]);
    *(ushort4*)(wt + (size_t)(n0 + nr) * 1024 + f0 + c4) = h;
  }
}

// ---------------- fused QKV GEMM: [32768,1024] @ [1024,1280] + bias ----------------
__global__ __launch_bounds__(256, 2) void gemm_qkv_k(
    const float* __restrict__ x, const u16* __restrict__ wt,
    const float* __restrict__ bc, u16* __restrict__ qkv, u16* __restrict__ vt) {
  __shared__ u16 sA[128 * 64];
  __shared__ u16 sB[128 * 64];
  char* sAc = (char*)sA;
  char* sBc = (char*)sB;
  const int t = threadIdx.x;
  const int w = t >> 6, lane = t & 63;
  const int wr = w >> 1, wc = w & 1;
  const int lm = lane & 15, lg = lane >> 4;
  const int m0 = blockIdx.x * 128;
  const f32x4 FZ = {0.f, 0.f, 0.f, 0.f};

  const int arow = t >> 4;
  const float* xb = x + (size_t)(m0 + arow) * 1024 + (t & 15) * 4;
  const int aswz = ((t >> 4) & 7) << 4;
  const int brow = t >> 3;
  const int bcol = 8 * ((t & 7) ^ ((t >> 3) & 7));
  const int kswz = (lm & 7) << 4;

  for (int nt = blockIdx.y * 5; nt < blockIdx.y * 5 + 5; ++nt) {
    const int n0 = nt * 128;
    f32x4 acc[4][4];
    #pragma unroll
    for (int mi = 0; mi < 4; ++mi)
      #pragma unroll
      for (int ni = 0; ni < 4; ++ni) acc[mi][ni] = FZ;
    const u16* wb = wt + (size_t)(n0 + brow) * 1024 + bcol;
    for (int kt = 0; kt < 16; ++kt) {
      const int k0 = kt * 64;
      #pragma unroll
      for (int i = 0; i < 8; ++i) {
        float4 v = *(const float4*)(xb + (size_t)(16 * i) * 1024 + k0);
        ushort4 h;
        h.x = f2bf(v.x); h.y = f2bf(v.y); h.z = f2bf(v.z); h.w = f2bf(v.w);
        *(ushort4*)(sAc + (((t + 256 * i) * 8) ^ aswz)) = h;
      }
      #pragma unroll
      for (int i = 0; i < 4; ++i)
        gll16(wb + (size_t)(32 * i) * 1024 + k0, sBc + w * 1024 + 4096 * i);
      __syncthreads();
      #pragma unroll
      for (int ks = 0; ks < 2; ++ks) {
        const int ka = (ks * 64 + lg * 16) ^ kswz;
        bf16x8 aF[4], bF[4];
        #pragma unroll
        for (int mi = 0; mi < 4; ++mi)
          aF[mi] = *(const bf16x8*)(sAc + (wr * 64 + mi * 16 + lm) * 128 + ka);
        #pragma unroll
        for (int ni = 0; ni < 4; ++ni)
          bF[ni] = *(const bf16x8*)(sBc + (wc * 64 + ni * 16 + lm) * 128 + ka);
        #pragma unroll
        for (int mi = 0; mi < 4; ++mi)
          #pragma unroll
          for (int ni = 0; ni < 4; ++ni)
            acc[mi][ni] = __builtin_amdgcn_mfma_f32_16x16x32_bf16(aF[mi], bF[ni], acc[mi][ni], 0, 0, 0);
      }
      __syncthreads();
    }
    #pragma unroll
    for (int ni = 0; ni < 4; ++ni) {
      const int col = n0 + wc * 64 + ni * 16 + lm;
      const float bias = bc[col];
      if (n0 < 256) {
        #pragma unroll
        for (int mi = 0; mi < 4; ++mi) {
          const int r0 = m0 + wr * 64 + mi * 16 + lg * 4;
          #pragma unroll
          for (int j = 0; j < 4; ++j)
            qkv[(size_t)(r0 + j) * 256 + col] = f2bf(acc[mi][ni][j] + bias);
        }
      } else {
        const int h = col - 256;
        #pragma unroll
        for (int mi = 0; mi < 4; ++mi) {
          const int r0 = m0 + wr * 64 + mi * 16 + lg * 4;
          const int bg = r0 >> 10;
          const int sb = r0 & 1023;
          ushort4 pk;
          pk.x = f2bf(acc[mi][ni][0] + bias);
          pk.y = f2bf(acc[mi][ni][1] + bias);
          pk.z = f2bf(acc[mi][ni][2] + bias);
          pk.w = f2bf(acc[mi][ni][3] + bias);
          *(ushort4*)(vt + ((size_t)(bg * 1024 + h) << 10) + sb) = pk;
        }
      }
    }
  }
}

// ---------------- flash attention + epilogue (gamma*O/l + x) ----------------
// 512 blocks (XCD-decoded), 512 threads = 8 waves: qw = w>>2 (32 q rows), hw = w&3 (256 h cols)
// Swapped QK^T; in-register P transform; K double-buffered in LDS (counted vmcnt);
// V fragments loaded DIRECTLY from global (vt layout makes them contiguous 16B) ->
// fragment traffic split across LDS pipe (K, ~1.9k cyc) and L1 pipe (V, ~2k cyc).
__global__ __launch_bounds__(512, 2) void attn_k(
    const u16* __restrict__ qk, const u16* __restrict__ vt,
    const float* __restrict__ x, const float* __restrict__ gam,
    float* __restrict__ out) {
  __shared__ u16 sK[2 * 32 * 128];   // 16 KB, rows 256B, XOR-swizzled by (row&7)<<4
  char* sKc = (char*)sK;
  const int t = threadIdx.x;
  const int w = t >> 6, lane = t & 63;
  const int qw = w >> 2, hw = w & 3;
  const int lm = lane & 15, lg = lane >> 4;
  const int bid = blockIdx.x;
  const int qt = (bid >> 3) & 15;
  const int bg = (((bid >> 7) & 3) << 3) | (bid & 7);
  const f32x4 FZ = {0.f, 0.f, 0.f, 0.f};

  // Q fragments (B operand): col = lm (q), k = lg*8+i
  bf16x8 qf[2][4];
  #pragma unroll
  for (int f = 0; f < 2; ++f)
    #pragma unroll
    for (int ks = 0; ks < 4; ++ks)
      qf[f][ks] = *(const bf16x8*)(qk +
          (size_t)(bg * 1024 + qt * 64 + qw * 32 + f * 16 + lm) * 256 + ks * 32 + lg * 8);

  f32x4 oacc[2][16];
  #pragma unroll
  for (int f = 0; f < 2; ++f)
    #pragma unroll
    for (int hc = 0; hc < 16; ++hc) oacc[f][hc] = FZ;
  float m_run[2] = {-3e38f, -3e38f}, l_run[2] = {0.f, 0.f};

  const char* qkc = (const char*)qk;
  const int krow = t >> 4;
  const char* ksrc = qkc + (size_t)(bg * 1024 + krow) * 512 + 256 + (((t & 15) ^ (krow & 7)) << 4);
  // V fragment base: vf(hc,kv0) = vt[bg][hw*256+hc*16+lm][kv0 + lg*8 .. +7]  (16B contiguous)
  const u16* vbase = vt + ((size_t)(bg * 1024 + hw * 256 + lm) << 10) + lg * 8;
  const int src0 = (2 * (lg & 1)) * 16 + lm;   // shuffle sources for P transform
  const int src1 = src0 + 16;
  const bool chlo = (lg < 2);

  // stage K kv-tile into buffer (1 gll16 per wave)
  auto stageK = [&](int buf, int kv0) {
    gll16(ksrc + (size_t)kv0 * 512, sKc + buf * 8192 + w * 1024);
  };

  int cur = 0;
  stageK(0, 0);
  for (int kv0 = 0; kv0 < 1024; kv0 += 32) {
    // barrier 1: all waves done reading the K buffer we are about to overwrite
    __builtin_amdgcn_s_barrier();
    __builtin_amdgcn_sched_barrier(0);
    if (kv0 + 32 < 1024) {
      stageK(cur ^ 1, kv0 + 32);
      asm volatile("s_waitcnt vmcnt(1)" ::: "memory");  // K(cur) landed; K(next) in flight
    } else {
      asm volatile("s_waitcnt vmcnt(0)" ::: "memory");
    }
    __builtin_amdgcn_sched_barrier(0);
    // barrier 2: K tile visible to all waves
    __builtin_amdgcn_s_barrier();

    const char* sKb = sKc + cur * 8192;

    // S^T = K @ Q^T  (swapped operands)
    f32x4 sc[2][2];
    sc[0][0] = FZ; sc[0][1] = FZ; sc[1][0] = FZ; sc[1][1] = FZ;
    __builtin_amdgcn_s_setprio(1);
    #pragma unroll
    for (int ch = 0; ch < 2; ++ch)
      #pragma unroll
      for (int ks = 0; ks < 4; ++ks) {
        bf16x8 kf = *(const bf16x8*)(sKb + (ch * 16 + lm) * 256 + ((ks * 64 + lg * 16) ^ ((lm & 7) << 4)));
        sc[0][ch] = __builtin_amdgcn_mfma_f32_16x16x32_bf16(kf, qf[0][ks], sc[0][ch], 0, 0, 0);
        sc[1][ch] = __builtin_amdgcn_mfma_f32_16x16x32_bf16(kf, qf[1][ks], sc[1][ch], 0, 0, 0);
      }
    __builtin_amdgcn_s_setprio(0);

    // in-register online softmax (per-lane column q=lm; reduce across lg via 2 shuffles)
    float pm[2];
    #pragma unroll
    for (int f = 0; f < 2; ++f) {
      float a0 = fmaxf(fmaxf(sc[f][0][0], sc[f][0][1]), fmaxf(sc[f][0][2], sc[f][0][3]));
      float a1 = fmaxf(fmaxf(sc[f][1][0], sc[f][1][1]), fmaxf(sc[f][1][2], sc[f][1][3]));
      float m8 = fmaxf(a0, a1);
      m8 = fmaxf(m8, __shfl_xor(m8, 16));
      m8 = fmaxf(m8, __shfl_xor(m8, 32));
      pm[f] = m8;
    }
    const bool grow = (pm[0] > m_run[0] + 8.0f) | (pm[1] > m_run[1] + 8.0f);
    if (__any(grow)) {  // defer-max rescale (rare)
      #pragma unroll
      for (int f = 0; f < 2; ++f) {
        const float mn = fmaxf(m_run[f], pm[f]);
        const float alf = __expf(m_run[f] - mn);
        m_run[f] = mn;
        l_run[f] *= alf;
        float ab[4];
        #pragma unroll
        for (int j = 0; j < 4; ++j) ab[j] = __shfl(alf, lg * 4 + j);
        #pragma unroll
        for (int hc = 0; hc < 16; ++hc)
          #pragma unroll
          for (int j = 0; j < 4; ++j) oacc[f][hc][j] *= ab[j];
      }
    }

    // P = exp(S - m), row-sum, and in-register D->A transform (no LDS, no barrier)
    bf16x8 pa[2];
    #pragma unroll
    for (int f = 0; f < 2; ++f) {
      float p0[4], p1[4];
      #pragma unroll
      for (int j = 0; j < 4; ++j) {
        p0[j] = __expf(sc[f][0][j] - m_run[f]);
        p1[j] = __expf(sc[f][1][j] - m_run[f]);
      }
      float rs = ((p0[0] + p0[1]) + (p0[2] + p0[3])) + ((p1[0] + p1[1]) + (p1[2] + p1[3]));
      rs += __shfl_xor(rs, 16);
      rs += __shfl_xor(rs, 32);
      l_run[f] += rs;
      unsigned c0 = pkbf(p0[0], p0[1]);
      unsigned c1 = pkbf(p0[2], p0[3]);
      unsigned c2 = pkbf(p1[0], p1[1]);
      unsigned c3 = pkbf(p1[2], p1[3]);
      unsigned a0 = __shfl(c0, src0), b0 = __shfl(c2, src0);
      unsigned a1 = __shfl(c1, src0), b1 = __shfl(c3, src0);
      unsigned a2 = __shfl(c0, src1), b2 = __shfl(c2, src1);
      unsigned a3 = __shfl(c1, src1), b3 = __shfl(c3, src1);
      u32x4 pw;
      pw.x = chlo ? a0 : b0;
      pw.y = chlo ? a1 : b1;
      pw.z = chlo ? a2 : b2;
      pw.w = chlo ? a3 : b3;
      pa[f] = __builtin_bit_cast(bf16x8, pw);
    }

    // O += P @ V   (V fragments straight from global; L1-resident, reused by wave pairs)
    __builtin_amdgcn_s_setprio(1);
    #pragma unroll
    for (int hc = 0; hc < 16; ++hc) {
      bf16x8 vf = *(const bf16x8*)(vbase + hc * 16384 + kv0);
      oacc[0][hc] = __builtin_amdgcn_mfma_f32_16x16x32_bf16(pa[0], vf, oacc[0][hc], 0, 0, 0);
      oacc[1][hc] = __builtin_amdgcn_mfma_f32_16x16x32_bf16(pa[1], vf, oacc[1][hc], 0, 0, 0);
    }
    __builtin_amdgcn_s_setprio(0);
    cur ^= 1;
  }

  // epilogue: out = gamma * O/l + x
  const float g0 = gam[0];
  #pragma unroll
  for (int f = 0; f < 2; ++f) {
    float inv[4];
    #pragma unroll
    for (int j = 0; j < 4; ++j) inv[j] = 1.0f / __shfl(l_run[f], lg * 4 + j);
    #pragma unroll
    for (int j = 0; j < 4; ++j) {
      const size_t ro = (size_t)(bg * 1024 + qt * 64 + qw * 32 + f * 16 + lg * 4 + j) * 1024;
      #pragma unroll
      for (int hc = 0; hc < 16; ++hc) {
        const int col = hw * 256 + hc * 16 + lm;
        out[ro + col] = g0 * oacc[f][hc][j] * inv[j] + x[ro + col];
      }
    }
  }
}

extern "C" void kernel_launch(void* const* d_in, const int* in_sizes, int n_in,
                              void* d_out, int out_size, void* d_ws, size_t ws_size,
                              hipStream_t stream) {
  const float* x  = (const float*)d_in[0];
  const float* Wq = (const float*)d_in[1];
  const float* bq = (const float*)d_in[2];
  const float* Wk = (const float*)d_in[3];
  const float* bk = (const float*)d_in[4];
  const float* Wv = (const float*)d_in[5];
  const float* bv = (const float*)d_in[6];
  const float* gm = (const float*)d_in[7];
  float* out = (float*)d_out;

  char* ws = (char*)d_ws;
  u16*   wt = (u16*)(ws);                 // 2,621,440 B
  float* bc = (float*)(ws + 2621440);     // 5,120 B
  u16*   qk = (u16*)(ws + 2626560);       // 16,777,216 B
  u16*   vt = (u16*)(ws + 19403776);      // 67,108,864 B

  build_bias_k<<<5, 256, 0, stream>>>(bq, bk, bv, bc);
  transpose_w_k<<<dim3(20, 16), 256, 0, stream>>>(Wq, Wk, Wv, wt);
  gemm_qkv_k<<<dim3(256, 2), 256, 0, stream>>>(x, wt, bc, qk, vt);
  attn_k<<<dim3(512), 512, 0, stream>>>(qk, vt, x, gm, out);
}

// Round 6
// 332.432 us; speedup vs baseline: 1.5700x; 1.5700x over previous
//
#include <hip/hip_runtime.h>

typedef unsigned short u16;
typedef __attribute__((ext_vector_type(8))) short bf16x8;
typedef __attribute__((ext_vector_type(4))) float f32x4;

__device__ __forceinline__ u16 f2bf(float f) {
  unsigned u = __builtin_bit_cast(unsigned, f);
  u += 0x7fffu + ((u >> 16) & 1u);
  return (u16)(u >> 16);
}

__device__ __forceinline__ unsigned pkbf(float lo, float hi) {
  unsigned r;
  asm("v_cvt_pk_bf16_f32 %0, %1, %2" : "=v"(r) : "v"(lo), "v"(hi));
  return r;
}

__device__ __forceinline__ void gll16(const void* g, void* l) {
  __builtin_amdgcn_global_load_lds((const __attribute__((address_space(1))) void*)g,
                                   (__attribute__((address_space(3))) void*)l, 16, 0, 0);
}

// ---------------- bias concat: bc[1280] = [bq | bk | bv] ----------------
__global__ void build_bias_k(const float* __restrict__ bq, const float* __restrict__ bk,
                             const float* __restrict__ bv, float* __restrict__ bc) {
  int i = blockIdx.x * 256 + threadIdx.x;
  if (i < 1280) bc[i] = (i < 128) ? bq[i] : ((i < 256) ? bk[i - 128] : bv[i - 256]);
}

// ------- weight transpose: wt[n][f] bf16, n in [0,1280), f in [0,1024) -------
__global__ void transpose_w_k(const float* __restrict__ Wq, const float* __restrict__ Wk,
                              const float* __restrict__ Wv, u16* __restrict__ wt) {
  __shared__ float tile[64][65];
  const int n0 = blockIdx.x * 64;
  const int f0 = blockIdx.y * 64;
  const int t = threadIdx.x;
  const float* src; int ld, coff;
  if (n0 < 128)      { src = Wq; ld = 128;  coff = n0; }
  else if (n0 < 256) { src = Wk; ld = 128;  coff = n0 - 128; }
  else               { src = Wv; ld = 1024; coff = n0 - 256; }
  const int r = t >> 4, c4 = (t & 15) * 4;
  #pragma unroll
  for (int i = 0; i < 4; ++i) {
    float4 v = *(const float4*)(src + (size_t)(f0 + r + 16 * i) * ld + coff + c4);
    tile[r + 16 * i][c4 + 0] = v.x;
    tile[r + 16 * i][c4 + 1] = v.y;
    tile[r + 16 * i][c4 + 2] = v.z;
    tile[r + 16 * i][c4 + 3] = v.w;
  }
  __syncthreads();
  #pragma unroll
  for (int i = 0; i < 4; ++i) {
    const int nr = r + 16 * i;
    ushort4 h;
    h.x = f2bf(tile[c4 + 0][nr]);
    h.y = f2bf(tile[c4 + 1][nr]);
    h.z = f2bf(tile[c4 + 2][nr]);
    h.w = f2bf(tile[c4 + 3][nr]);
    *(ushort4*)(wt + (size_t)(n0 + nr) * 1024 + f0 + c4) = h;
  }
}

// ---------------- fused QKV GEMM: [32768,1024] @ [1024,1280] + bias ----------------
__global__ __launch_bounds__(256, 2) void gemm_qkv_k(
    const float* __restrict__ x, const u16* __restrict__ wt,
    const float* __restrict__ bc, u16* __restrict__ qkv, u16* __restrict__ vt) {
  __shared__ u16 sA[128 * 64];
  __shared__ u16 sB[128 * 64];
  char* sAc = (char*)sA;
  char* sBc = (char*)sB;
  const int t = threadIdx.x;
  const int w = t >> 6, lane = t & 63;
  const int wr = w >> 1, wc = w & 1;
  const int lm = lane & 15, lg = lane >> 4;
  const int m0 = blockIdx.x * 128;
  const f32x4 FZ = {0.f, 0.f, 0.f, 0.f};

  const int arow = t >> 4;
  const float* xb = x + (size_t)(m0 + arow) * 1024 + (t & 15) * 4;
  const int aswz = ((t >> 4) & 7) << 4;
  const int brow = t >> 3;
  const int bcol = 8 * ((t & 7) ^ ((t >> 3) & 7));
  const int kswz = (lm & 7) << 4;

  for (int nt = blockIdx.y * 5; nt < blockIdx.y * 5 + 5; ++nt) {
    const int n0 = nt * 128;
    f32x4 acc[4][4];
    #pragma unroll
    for (int mi = 0; mi < 4; ++mi)
      #pragma unroll
      for (int ni = 0; ni < 4; ++ni) acc[mi][ni] = FZ;
    const u16* wb = wt + (size_t)(n0 + brow) * 1024 + bcol;
    for (int kt = 0; kt < 16; ++kt) {
      const int k0 = kt * 64;
      #pragma unroll
      for (int i = 0; i < 8; ++i) {
        float4 v = *(const float4*)(xb + (size_t)(16 * i) * 1024 + k0);
        ushort4 h;
        h.x = f2bf(v.x); h.y = f2bf(v.y); h.z = f2bf(v.z); h.w = f2bf(v.w);
        *(ushort4*)(sAc + (((t + 256 * i) * 8) ^ aswz)) = h;
      }
      #pragma unroll
      for (int i = 0; i < 4; ++i)
        gll16(wb + (size_t)(32 * i) * 1024 + k0, sBc + w * 1024 + 4096 * i);
      __syncthreads();
      #pragma unroll
      for (int ks = 0; ks < 2; ++ks) {
        const int ka = (ks * 64 + lg * 16) ^ kswz;
        bf16x8 aF[4], bF[4];
        #pragma unroll
        for (int mi = 0; mi < 4; ++mi)
          aF[mi] = *(const bf16x8*)(sAc + (wr * 64 + mi * 16 + lm) * 128 + ka);
        #pragma unroll
        for (int ni = 0; ni < 4; ++ni)
          bF[ni] = *(const bf16x8*)(sBc + (wc * 64 + ni * 16 + lm) * 128 + ka);
        #pragma unroll
        for (int mi = 0; mi < 4; ++mi)
          #pragma unroll
          for (int ni = 0; ni < 4; ++ni)
            acc[mi][ni] = __builtin_amdgcn_mfma_f32_16x16x32_bf16(aF[mi], bF[ni], acc[mi][ni], 0, 0, 0);
      }
      __syncthreads();
    }
    #pragma unroll
    for (int ni = 0; ni < 4; ++ni) {
      const int col = n0 + wc * 64 + ni * 16 + lm;
      const float bias = bc[col];
      if (n0 < 256) {
        #pragma unroll
        for (int mi = 0; mi < 4; ++mi) {
          const int r0 = m0 + wr * 64 + mi * 16 + lg * 4;
          #pragma unroll
          for (int j = 0; j < 4; ++j)
            qkv[(size_t)(r0 + j) * 256 + col] = f2bf(acc[mi][ni][j] + bias);
        }
      } else {
        const int h = col - 256;
        #pragma unroll
        for (int mi = 0; mi < 4; ++mi) {
          const int r0 = m0 + wr * 64 + mi * 16 + lg * 4;
          const int bg = r0 >> 10;
          const int sb = r0 & 1023;
          ushort4 pk;
          pk.x = f2bf(acc[mi][ni][0] + bias);
          pk.y = f2bf(acc[mi][ni][1] + bias);
          pk.z = f2bf(acc[mi][ni][2] + bias);
          pk.w = f2bf(acc[mi][ni][3] + bias);
          *(ushort4*)(vt + ((size_t)(bg * 1024 + h) << 10) + sb) = pk;
        }
      }
    }
  }
}

// ---------------- QK^T + exact softmax -> normalized P (bf16) ----------------
// grid 1024 (XCD-decoded: bg fixed per XCD group), 512 threads = 8 waves.
// Block owns 32 q rows x full 1024 kv. Wave w owns kv in [w*128, w*128+128).
// Swapped mfma(K,Q): lane holds S^T[kv=ch*16+lg*4+j][q=qc*16+lm] -> whole row in regs,
// exact (non-online) softmax via one LDS max/sum exchange. P written pre-normalized.
__global__ __launch_bounds__(512, 2) void qks_k(const u16* __restrict__ qk,
                                                u16* __restrict__ P) {
  __shared__ float smax[8][32];
  __shared__ float ssum[8][32];
  const int t = threadIdx.x;
  const int w = t >> 6, lane = t & 63;
  const int lm = lane & 15, lg = lane >> 4;
  const int bid = blockIdx.x;
  const int qt = (bid >> 3) & 31;
  const int bg = (((bid >> 8) & 3) << 3) | (bid & 7);
  const f32x4 FZ = {0.f, 0.f, 0.f, 0.f};

  // Q fragments (B operand): col = q = lm, k = lg*8+i  (q-proj = elements 0..127)
  bf16x8 qf[2][4];
  #pragma unroll
  for (int qc = 0; qc < 2; ++qc)
    #pragma unroll
    for (int ks = 0; ks < 4; ++ks)
      qf[qc][ks] = *(const bf16x8*)(qk +
          (size_t)(bg * 1024 + qt * 32 + qc * 16 + lm) * 256 + ks * 32 + lg * 8);

  // S^T accumulation: sc[ch][qc] covers kv chunk ch*16, q chunk qc*16
  f32x4 sc[8][2];
  #pragma unroll
  for (int ch = 0; ch < 8; ++ch) { sc[ch][0] = FZ; sc[ch][1] = FZ; }
  const u16* kbase = qk + (size_t)(bg * 1024 + w * 128) * 256 + 128;  // k-proj = elems 128..255
  #pragma unroll
  for (int ch = 0; ch < 8; ++ch) {
    bf16x8 kf[4];
    #pragma unroll
    for (int ks = 0; ks < 4; ++ks)
      kf[ks] = *(const bf16x8*)(kbase + (size_t)(ch * 16 + lm) * 256 + ks * 32 + lg * 8);
    #pragma unroll
    for (int ks = 0; ks < 4; ++ks) {
      sc[ch][0] = __builtin_amdgcn_mfma_f32_16x16x32_bf16(kf[ks], qf[0][ks], sc[ch][0], 0, 0, 0);
      sc[ch][1] = __builtin_amdgcn_mfma_f32_16x16x32_bf16(kf[ks], qf[1][ks], sc[ch][1], 0, 0, 0);
    }
  }

  // per-wave max for each q (lane's q = qc*16+lm), reduced across lg via shuffles
  float mx[2];
  #pragma unroll
  for (int qc = 0; qc < 2; ++qc) {
    float m = sc[0][qc][0];
    #pragma unroll
    for (int ch = 0; ch < 8; ++ch)
      #pragma unroll
      for (int j = 0; j < 4; ++j) m = fmaxf(m, sc[ch][qc][j]);
    m = fmaxf(m, __shfl_xor(m, 16));
    m = fmaxf(m, __shfl_xor(m, 32));
    mx[qc] = m;
  }
  if (lg == 0) { smax[w][lm] = mx[0]; smax[w][16 + lm] = mx[1]; }
  __syncthreads();
  float gm[2];
  #pragma unroll
  for (int qc = 0; qc < 2; ++qc) {
    float m = smax[0][qc * 16 + lm];
    #pragma unroll
    for (int wp = 1; wp < 8; ++wp) m = fmaxf(m, smax[wp][qc * 16 + lm]);
    gm[qc] = m;
  }

  // exp + per-wave sum
  float ls[2] = {0.f, 0.f};
  #pragma unroll
  for (int ch = 0; ch < 8; ++ch)
    #pragma unroll
    for (int qc = 0; qc < 2; ++qc) {
      f32x4 e;
      #pragma unroll
      for (int j = 0; j < 4; ++j) e[j] = __expf(sc[ch][qc][j] - gm[qc]);
      sc[ch][qc] = e;
      ls[qc] += (e[0] + e[1]) + (e[2] + e[3]);
    }
  #pragma unroll
  for (int qc = 0; qc < 2; ++qc) {
    ls[qc] += __shfl_xor(ls[qc], 16);
    ls[qc] += __shfl_xor(ls[qc], 32);
  }
  if (lg == 0) { ssum[w][lm] = ls[0]; ssum[w][16 + lm] = ls[1]; }
  __syncthreads();
  float inv[2];
  #pragma unroll
  for (int qc = 0; qc < 2; ++qc) {
    float s = ssum[0][qc * 16 + lm];
    #pragma unroll
    for (int wp = 1; wp < 8; ++wp) s += ssum[wp][qc * 16 + lm];
    inv[qc] = 1.0f / s;
  }

  // write normalized P[bg][q][kv] bf16; lane's kv = w*128 + ch*16 + lg*4 + {0..3}
  #pragma unroll
  for (int qc = 0; qc < 2; ++qc) {
    u16* pr = P + ((size_t)(bg * 1024 + qt * 32 + qc * 16 + lm) << 10) + w * 128 + lg * 4;
    #pragma unroll
    for (int ch = 0; ch < 8; ++ch) {
      uint2 u;
      u.x = pkbf(sc[ch][qc][0] * inv[qc], sc[ch][qc][1] * inv[qc]);
      u.y = pkbf(sc[ch][qc][2] * inv[qc], sc[ch][qc][3] * inv[qc]);
      *(uint2*)(pr + ch * 16) = u;
    }
  }
}

// ---------------- PV GEMM + epilogue: out = gamma * (P @ V) + x ----------------
// Batched per bg: [1024q,1024kv] @ [1024kv,1024h]. A = P rows, B^T = vt rows.
// Same 128x128xBK64 MFMA structure as gemm_qkv_k; both tiles staged via gll16.
__global__ __launch_bounds__(256, 2) void pv_k(
    const u16* __restrict__ P, const u16* __restrict__ vt,
    const float* __restrict__ x, const float* __restrict__ gam,
    float* __restrict__ out) {
  __shared__ u16 sA[128 * 64];
  __shared__ u16 sB[128 * 64];
  char* sAc = (char*)sA;
  char* sBc = (char*)sB;
  const int t = threadIdx.x;
  const int w = t >> 6, lane = t & 63;
  const int wr = w >> 1, wc = w & 1;
  const int lm = lane & 15, lg = lane >> 4;
  const int bid = blockIdx.x;
  const int bg = (((bid >> 9) & 3) << 3) | (bid & 7);
  const int qb = (bid >> 6) & 7;
  const int hb = (bid >> 3) & 7;
  const int m0 = qb * 128, n0 = hb * 128;
  const f32x4 FZ = {0.f, 0.f, 0.f, 0.f};

  const int brow = t >> 3;
  const int bcol = 8 * ((t & 7) ^ ((t >> 3) & 7));
  const int kswz = (lm & 7) << 4;
  const u16* pb = P + ((size_t)(bg * 1024 + m0 + brow) << 10) + bcol;
  const u16* wb = vt + ((size_t)(bg * 1024 + n0 + brow) << 10) + bcol;

  f32x4 acc[4][4];
  #pragma unroll
  for (int mi = 0; mi < 4; ++mi)
    #pragma unroll
    for (int ni = 0; ni < 4; ++ni) acc[mi][ni] = FZ;

  for (int kt = 0; kt < 16; ++kt) {
    const int k0 = kt * 64;
    #pragma unroll
    for (int i = 0; i < 4; ++i) {
      gll16(pb + (size_t)(32 * i) * 1024 + k0, sAc + w * 1024 + 4096 * i);
      gll16(wb + (size_t)(32 * i) * 1024 + k0, sBc + w * 1024 + 4096 * i);
    }
    __syncthreads();
    #pragma unroll
    for (int ks = 0; ks < 2; ++ks) {
      const int ka = (ks * 64 + lg * 16) ^ kswz;
      bf16x8 aF[4], bF[4];
      #pragma unroll
      for (int mi = 0; mi < 4; ++mi)
        aF[mi] = *(const bf16x8*)(sAc + (wr * 64 + mi * 16 + lm) * 128 + ka);
      #pragma unroll
      for (int ni = 0; ni < 4; ++ni)
        bF[ni] = *(const bf16x8*)(sBc + (wc * 64 + ni * 16 + lm) * 128 + ka);
      #pragma unroll
      for (int mi = 0; mi < 4; ++mi)
        #pragma unroll
        for (int ni = 0; ni < 4; ++ni)
          acc[mi][ni] = __builtin_amdgcn_mfma_f32_16x16x32_bf16(aF[mi], bF[ni], acc[mi][ni], 0, 0, 0);
    }
    __syncthreads();
  }

  // epilogue: out = gamma*acc + x
  const float g0 = gam[0];
  #pragma unroll
  for (int mi = 0; mi < 4; ++mi)
    #pragma unroll
    for (int j = 0; j < 4; ++j) {
      const size_t row = (size_t)(bg * 1024 + m0 + wr * 64 + mi * 16 + lg * 4 + j);
      #pragma unroll
      for (int ni = 0; ni < 4; ++ni) {
        const int col = n0 + wc * 64 + ni * 16 + lm;
        const size_t idx = row * 1024 + col;
        out[idx] = g0 * acc[mi][ni][j] + x[idx];
      }
    }
}

extern "C" void kernel_launch(void* const* d_in, const int* in_sizes, int n_in,
                              void* d_out, int out_size, void* d_ws, size_t ws_size,
                              hipStream_t stream) {
  const float* x  = (const float*)d_in[0];
  const float* Wq = (const float*)d_in[1];
  const float* bq = (const float*)d_in[2];
  const float* Wk = (const float*)d_in[3];
  const float* bk = (const float*)d_in[4];
  const float* Wv = (const float*)d_in[5];
  const float* bv = (const float*)d_in[6];
  const float* gm = (const float*)d_in[7];
  float* out = (float*)d_out;

  char* ws = (char*)d_ws;
  u16*   wt = (u16*)(ws);                 // 2,621,440 B
  float* bc = (float*)(ws + 2621440);     // 5,120 B
  u16*   qk = (u16*)(ws + 2626560);       // 16,777,216 B
  u16*   vt = (u16*)(ws + 19403776);      // 67,108,864 B
  u16*   Pm = (u16*)(ws + 86512640);      // 67,108,864 B  (total ~153.6 MB)

  build_bias_k<<<5, 256, 0, stream>>>(bq, bk, bv, bc);
  transpose_w_k<<<dim3(20, 16), 256, 0, stream>>>(Wq, Wk, Wv, wt);
  gemm_qkv_k<<<dim3(256, 2), 256, 0, stream>>>(x, wt, bc, qk, vt);
  qks_k<<<dim3(1024), 512, 0, stream>>>(qk, Pm);
  pv_k<<<dim3(2048), 256, 0, stream>>>(Pm, vt, x, gm, out);
}

// Round 7
// 323.048 us; speedup vs baseline: 1.6156x; 1.0290x over previous
//
#include <hip/hip_runtime.h>

typedef unsigned short u16;
typedef __attribute__((ext_vector_type(8))) short bf16x8;
typedef __attribute__((ext_vector_type(4))) float f32x4;

__device__ __forceinline__ u16 f2bf(float f) {
  unsigned u = __builtin_bit_cast(unsigned, f);
  u += 0x7fffu + ((u >> 16) & 1u);
  return (u16)(u >> 16);
}

__device__ __forceinline__ unsigned pkbf(float lo, float hi) {
  unsigned r;
  asm("v_cvt_pk_bf16_f32 %0, %1, %2" : "=v"(r) : "v"(lo), "v"(hi));
  return r;
}

__device__ __forceinline__ void gll16(const void* g, void* l) {
  __builtin_amdgcn_global_load_lds((const __attribute__((address_space(1))) void*)g,
                                   (__attribute__((address_space(3))) void*)l, 16, 0, 0);
}

// ---------------- x -> bf16 (one-time) ----------------
__global__ void xbf_k(const float* __restrict__ x, u16* __restrict__ xb) {
  const size_t i = ((size_t)blockIdx.x * 256 + threadIdx.x) * 8;
  float4 a = *(const float4*)(x + i);
  float4 b = *(const float4*)(x + i + 4);
  uint4 u;
  u.x = pkbf(a.x, a.y);
  u.y = pkbf(a.z, a.w);
  u.z = pkbf(b.x, b.y);
  u.w = pkbf(b.z, b.w);
  *(uint4*)(xb + i) = u;
}

// ---------------- bias concat: bc[1280] = [bq | bk | bv] ----------------
__global__ void build_bias_k(const float* __restrict__ bq, const float* __restrict__ bk,
                             const float* __restrict__ bv, float* __restrict__ bc) {
  int i = blockIdx.x * 256 + threadIdx.x;
  if (i < 1280) bc[i] = (i < 128) ? bq[i] : ((i < 256) ? bk[i - 128] : bv[i - 256]);
}

// ------- weight transpose: wt[n][f] bf16, n in [0,1280), f in [0,1024) -------
__global__ void transpose_w_k(const float* __restrict__ Wq, const float* __restrict__ Wk,
                              const float* __restrict__ Wv, u16* __restrict__ wt) {
  __shared__ float tile[64][65];
  const int n0 = blockIdx.x * 64;
  const int f0 = blockIdx.y * 64;
  const int t = threadIdx.x;
  const float* src; int ld, coff;
  if (n0 < 128)      { src = Wq; ld = 128;  coff = n0; }
  else if (n0 < 256) { src = Wk; ld = 128;  coff = n0 - 128; }
  else               { src = Wv; ld = 1024; coff = n0 - 256; }
  const int r = t >> 4, c4 = (t & 15) * 4;
  #pragma unroll
  for (int i = 0; i < 4; ++i) {
    float4 v = *(const float4*)(src + (size_t)(f0 + r + 16 * i) * ld + coff + c4);
    tile[r + 16 * i][c4 + 0] = v.x;
    tile[r + 16 * i][c4 + 1] = v.y;
    tile[r + 16 * i][c4 + 2] = v.z;
    tile[r + 16 * i][c4 + 3] = v.w;
  }
  __syncthreads();
  #pragma unroll
  for (int i = 0; i < 4; ++i) {
    const int nr = r + 16 * i;
    ushort4 h;
    h.x = f2bf(tile[c4 + 0][nr]);
    h.y = f2bf(tile[c4 + 1][nr]);
    h.z = f2bf(tile[c4 + 2][nr]);
    h.w = f2bf(tile[c4 + 3][nr]);
    *(ushort4*)(wt + (size_t)(n0 + nr) * 1024 + f0 + c4) = h;
  }
}

// ---------------- fused QKV GEMM: [32768,1024]bf16 @ [1024,1280] + bias ----------------
// 512 blocks: paired decode puts the 2 y-groups sharing an x slab on the same XCD.
// Double-buffered LDS (A and B both via global_load_lds), counted vmcnt(8).
__global__ __launch_bounds__(256, 2) void gemm_qkv_k(
    const u16* __restrict__ xb, const u16* __restrict__ wt,
    const float* __restrict__ bc, u16* __restrict__ qkv, u16* __restrict__ vt) {
  __shared__ u16 sA[2 * 128 * 64];
  __shared__ u16 sB[2 * 128 * 64];
  char* sAc = (char*)sA;
  char* sBc = (char*)sB;
  const int t = threadIdx.x;
  const int w = t >> 6, lane = t & 63;
  const int wr = w >> 1, wc = w & 1;
  const int lm = lane & 15, lg = lane >> 4;
  const int bid = blockIdx.x;
  const int mb = ((bid & ~15) >> 1) | (bid & 7);  // 0..255
  const int yg = (bid >> 3) & 1;
  const int m0 = mb * 128;
  const f32x4 FZ = {0.f, 0.f, 0.f, 0.f};

  const int brow = t >> 3;                          // 0..31
  const int bcol = 8 * ((t & 7) ^ ((t >> 3) & 7));  // pre-swizzled source col (elems)
  const int kswz = (lm & 7) << 4;
  const u16* ab = xb + (size_t)(m0 + brow) * 1024 + bcol;

  for (int nt = yg * 5; nt < yg * 5 + 5; ++nt) {
    const int n0 = nt * 128;
    f32x4 acc[4][4];
    #pragma unroll
    for (int mi = 0; mi < 4; ++mi)
      #pragma unroll
      for (int ni = 0; ni < 4; ++ni) acc[mi][ni] = FZ;
    const u16* wb = wt + (size_t)(n0 + brow) * 1024 + bcol;

    // stage K-step k0 into buffer buf: 4 A + 4 B gll16 per wave
    auto stage = [&](int buf, int k0) {
      char* da = sAc + buf * 16384 + w * 1024;
      char* db = sBc + buf * 16384 + w * 1024;
      #pragma unroll
      for (int i = 0; i < 4; ++i) {
        gll16(ab + (size_t)(32 * i) * 1024 + k0, da + 4096 * i);
        gll16(wb + (size_t)(32 * i) * 1024 + k0, db + 4096 * i);
      }
    };

    int buf = 0;
    stage(0, 0);
    for (int kt = 0; kt < 16; ++kt) {
      // barrier 1: all waves done reading the buffer about to be overwritten
      __builtin_amdgcn_s_barrier();
      __builtin_amdgcn_sched_barrier(0);
      if (kt < 15) {
        stage(buf ^ 1, (kt + 1) * 64);
        asm volatile("s_waitcnt vmcnt(8)" ::: "memory");  // cur landed; next 8 in flight
      } else {
        asm volatile("s_waitcnt vmcnt(0)" ::: "memory");
      }
      __builtin_amdgcn_sched_barrier(0);
      // barrier 2: tile visible to all waves
      __builtin_amdgcn_s_barrier();

      const char* sAb = sAc + buf * 16384;
      const char* sBb = sBc + buf * 16384;
      #pragma unroll
      for (int ks = 0; ks < 2; ++ks) {
        const int ka = (ks * 64 + lg * 16) ^ kswz;
        bf16x8 aF[4], bF[4];
        #pragma unroll
        for (int mi = 0; mi < 4; ++mi)
          aF[mi] = *(const bf16x8*)(sAb + (wr * 64 + mi * 16 + lm) * 128 + ka);
        #pragma unroll
        for (int ni = 0; ni < 4; ++ni)
          bF[ni] = *(const bf16x8*)(sBb + (wc * 64 + ni * 16 + lm) * 128 + ka);
        #pragma unroll
        for (int mi = 0; mi < 4; ++mi)
          #pragma unroll
          for (int ni = 0; ni < 4; ++ni)
            acc[mi][ni] = __builtin_amdgcn_mfma_f32_16x16x32_bf16(aF[mi], bF[ni], acc[mi][ni], 0, 0, 0);
      }
      buf ^= 1;
    }

    // epilogue: bias + store (C/D layout: col = lane&15, row = (lane>>4)*4 + j)
    #pragma unroll
    for (int ni = 0; ni < 4; ++ni) {
      const int col = n0 + wc * 64 + ni * 16 + lm;
      const float bias = bc[col];
      if (n0 < 256) {
        #pragma unroll
        for (int mi = 0; mi < 4; ++mi) {
          const int r0 = m0 + wr * 64 + mi * 16 + lg * 4;
          #pragma unroll
          for (int j = 0; j < 4; ++j)
            qkv[(size_t)(r0 + j) * 256 + col] = f2bf(acc[mi][ni][j] + bias);
        }
      } else {
        const int h = col - 256;
        #pragma unroll
        for (int mi = 0; mi < 4; ++mi) {
          const int r0 = m0 + wr * 64 + mi * 16 + lg * 4;
          const int bg = r0 >> 10;
          const int sb = r0 & 1023;
          ushort4 pk;
          pk.x = f2bf(acc[mi][ni][0] + bias);
          pk.y = f2bf(acc[mi][ni][1] + bias);
          pk.z = f2bf(acc[mi][ni][2] + bias);
          pk.w = f2bf(acc[mi][ni][3] + bias);
          *(ushort4*)(vt + ((size_t)(bg * 1024 + h) << 10) + sb) = pk;
        }
      }
    }
  }
}

// ---------------- QK^T + exact softmax -> normalized P (bf16) ----------------
__global__ __launch_bounds__(512, 2) void qks_k(const u16* __restrict__ qk,
                                                u16* __restrict__ P) {
  __shared__ float smax[8][32];
  __shared__ float ssum[8][32];
  const int t = threadIdx.x;
  const int w = t >> 6, lane = t & 63;
  const int lm = lane & 15, lg = lane >> 4;
  const int bid = blockIdx.x;
  const int qt = (bid >> 3) & 31;
  const int bg = (((bid >> 8) & 3) << 3) | (bid & 7);
  const f32x4 FZ = {0.f, 0.f, 0.f, 0.f};

  bf16x8 qf[2][4];
  #pragma unroll
  for (int qc = 0; qc < 2; ++qc)
    #pragma unroll
    for (int ks = 0; ks < 4; ++ks)
      qf[qc][ks] = *(const bf16x8*)(qk +
          (size_t)(bg * 1024 + qt * 32 + qc * 16 + lm) * 256 + ks * 32 + lg * 8);

  f32x4 sc[8][2];
  #pragma unroll
  for (int ch = 0; ch < 8; ++ch) { sc[ch][0] = FZ; sc[ch][1] = FZ; }
  const u16* kbase = qk + (size_t)(bg * 1024 + w * 128) * 256 + 128;
  #pragma unroll
  for (int ch = 0; ch < 8; ++ch) {
    bf16x8 kf[4];
    #pragma unroll
    for (int ks = 0; ks < 4; ++ks)
      kf[ks] = *(const bf16x8*)(kbase + (size_t)(ch * 16 + lm) * 256 + ks * 32 + lg * 8);
    #pragma unroll
    for (int ks = 0; ks < 4; ++ks) {
      sc[ch][0] = __builtin_amdgcn_mfma_f32_16x16x32_bf16(kf[ks], qf[0][ks], sc[ch][0], 0, 0, 0);
      sc[ch][1] = __builtin_amdgcn_mfma_f32_16x16x32_bf16(kf[ks], qf[1][ks], sc[ch][1], 0, 0, 0);
    }
  }

  float mx[2];
  #pragma unroll
  for (int qc = 0; qc < 2; ++qc) {
    float m = sc[0][qc][0];
    #pragma unroll
    for (int ch = 0; ch < 8; ++ch)
      #pragma unroll
      for (int j = 0; j < 4; ++j) m = fmaxf(m, sc[ch][qc][j]);
    m = fmaxf(m, __shfl_xor(m, 16));
    m = fmaxf(m, __shfl_xor(m, 32));
    mx[qc] = m;
  }
  if (lg == 0) { smax[w][lm] = mx[0]; smax[w][16 + lm] = mx[1]; }
  __syncthreads();
  float gm[2];
  #pragma unroll
  for (int qc = 0; qc < 2; ++qc) {
    float m = smax[0][qc * 16 + lm];
    #pragma unroll
    for (int wp = 1; wp < 8; ++wp) m = fmaxf(m, smax[wp][qc * 16 + lm]);
    gm[qc] = m;
  }

  float ls[2] = {0.f, 0.f};
  #pragma unroll
  for (int ch = 0; ch < 8; ++ch)
    #pragma unroll
    for (int qc = 0; qc < 2; ++qc) {
      f32x4 e;
      #pragma unroll
      for (int j = 0; j < 4; ++j) e[j] = __expf(sc[ch][qc][j] - gm[qc]);
      sc[ch][qc] = e;
      ls[qc] += (e[0] + e[1]) + (e[2] + e[3]);
    }
  #pragma unroll
  for (int qc = 0; qc < 2; ++qc) {
    ls[qc] += __shfl_xor(ls[qc], 16);
    ls[qc] += __shfl_xor(ls[qc], 32);
  }
  if (lg == 0) { ssum[w][lm] = ls[0]; ssum[w][16 + lm] = ls[1]; }
  __syncthreads();
  float inv[2];
  #pragma unroll
  for (int qc = 0; qc < 2; ++qc) {
    float s = ssum[0][qc * 16 + lm];
    #pragma unroll
    for (int wp = 1; wp < 8; ++wp) s += ssum[wp][qc * 16 + lm];
    inv[qc] = 1.0f / s;
  }

  #pragma unroll
  for (int qc = 0; qc < 2; ++qc) {
    u16* pr = P + ((size_t)(bg * 1024 + qt * 32 + qc * 16 + lm) << 10) + w * 128 + lg * 4;
    #pragma unroll
    for (int ch = 0; ch < 8; ++ch) {
      uint2 u;
      u.x = pkbf(sc[ch][qc][0] * inv[qc], sc[ch][qc][1] * inv[qc]);
      u.y = pkbf(sc[ch][qc][2] * inv[qc], sc[ch][qc][3] * inv[qc]);
      *(uint2*)(pr + ch * 16) = u;
    }
  }
}

// ---------------- PV GEMM + epilogue: out = gamma * (P @ V) + x ----------------
// Double-buffered LDS + counted vmcnt(8), same pipeline as gemm_qkv_k.
__global__ __launch_bounds__(256, 2) void pv_k(
    const u16* __restrict__ P, const u16* __restrict__ vt,
    const float* __restrict__ x, const float* __restrict__ gam,
    float* __restrict__ out) {
  __shared__ u16 sA[2 * 128 * 64];
  __shared__ u16 sB[2 * 128 * 64];
  char* sAc = (char*)sA;
  char* sBc = (char*)sB;
  const int t = threadIdx.x;
  const int w = t >> 6, lane = t & 63;
  const int wr = w >> 1, wc = w & 1;
  const int lm = lane & 15, lg = lane >> 4;
  const int bid = blockIdx.x;
  const int bg = (((bid >> 9) & 3) << 3) | (bid & 7);
  const int qb = (bid >> 6) & 7;
  const int hb = (bid >> 3) & 7;
  const int m0 = qb * 128, n0 = hb * 128;
  const f32x4 FZ = {0.f, 0.f, 0.f, 0.f};

  const int brow = t >> 3;
  const int bcol = 8 * ((t & 7) ^ ((t >> 3) & 7));
  const int kswz = (lm & 7) << 4;
  const u16* pb = P + ((size_t)(bg * 1024 + m0 + brow) << 10) + bcol;
  const u16* wb = vt + ((size_t)(bg * 1024 + n0 + brow) << 10) + bcol;

  f32x4 acc[4][4];
  #pragma unroll
  for (int mi = 0; mi < 4; ++mi)
    #pragma unroll
    for (int ni = 0; ni < 4; ++ni) acc[mi][ni] = FZ;

  auto stage = [&](int buf, int k0) {
    char* da = sAc + buf * 16384 + w * 1024;
    char* db = sBc + buf * 16384 + w * 1024;
    #pragma unroll
    for (int i = 0; i < 4; ++i) {
      gll16(pb + (size_t)(32 * i) * 1024 + k0, da + 4096 * i);
      gll16(wb + (size_t)(32 * i) * 1024 + k0, db + 4096 * i);
    }
  };

  int buf = 0;
  stage(0, 0);
  for (int kt = 0; kt < 16; ++kt) {
    __builtin_amdgcn_s_barrier();
    __builtin_amdgcn_sched_barrier(0);
    if (kt < 15) {
      stage(buf ^ 1, (kt + 1) * 64);
      asm volatile("s_waitcnt vmcnt(8)" ::: "memory");
    } else {
      asm volatile("s_waitcnt vmcnt(0)" ::: "memory");
    }
    __builtin_amdgcn_sched_barrier(0);
    __builtin_amdgcn_s_barrier();

    const char* sAb = sAc + buf * 16384;
    const char* sBb = sBc + buf * 16384;
    #pragma unroll
    for (int ks = 0; ks < 2; ++ks) {
      const int ka = (ks * 64 + lg * 16) ^ kswz;
      bf16x8 aF[4], bF[4];
      #pragma unroll
      for (int mi = 0; mi < 4; ++mi)
        aF[mi] = *(const bf16x8*)(sAb + (wr * 64 + mi * 16 + lm) * 128 + ka);
      #pragma unroll
      for (int ni = 0; ni < 4; ++ni)
        bF[ni] = *(const bf16x8*)(sBb + (wc * 64 + ni * 16 + lm) * 128 + ka);
      #pragma unroll
      for (int mi = 0; mi < 4; ++mi)
        #pragma unroll
        for (int ni = 0; ni < 4; ++ni)
          acc[mi][ni] = __builtin_amdgcn_mfma_f32_16x16x32_bf16(aF[mi], bF[ni], acc[mi][ni], 0, 0, 0);
    }
    buf ^= 1;
  }

  // epilogue: out = gamma*acc + x
  const float g0 = gam[0];
  #pragma unroll
  for (int mi = 0; mi < 4; ++mi)
    #pragma unroll
    for (int j = 0; j < 4; ++j) {
      const size_t row = (size_t)(bg * 1024 + m0 + wr * 64 + mi * 16 + lg * 4 + j);
      #pragma unroll
      for (int ni = 0; ni < 4; ++ni) {
        const int col = n0 + wc * 64 + ni * 16 + lm;
        const size_t idx = row * 1024 + col;
        out[idx] = g0 * acc[mi][ni][j] + x[idx];
      }
    }
}

extern "C" void kernel_launch(void* const* d_in, const int* in_sizes, int n_in,
                              void* d_out, int out_size, void* d_ws, size_t ws_size,
                              hipStream_t stream) {
  const float* x  = (const float*)d_in[0];
  const float* Wq = (const float*)d_in[1];
  const float* bq = (const float*)d_in[2];
  const float* Wk = (const float*)d_in[3];
  const float* bk = (const float*)d_in[4];
  const float* Wv = (const float*)d_in[5];
  const float* bv = (const float*)d_in[6];
  const float* gm = (const float*)d_in[7];
  float* out = (float*)d_out;

  char* ws = (char*)d_ws;
  u16*   wt = (u16*)(ws);                 // 2,621,440 B
  float* bc = (float*)(ws + 2621440);     // 5,120 B
  u16*   qk = (u16*)(ws + 2626560);       // 16,777,216 B
  u16*   vt = (u16*)(ws + 19403776);      // 67,108,864 B
  u16*   Pm = (u16*)(ws + 86512640);      // 67,108,864 B
  u16*   xb = (u16*)(ws + 153621504);     // 67,108,864 B  (total ~220.7 MB)

  xbf_k<<<16384, 256, 0, stream>>>(x, xb);
  build_bias_k<<<5, 256, 0, stream>>>(bq, bk, bv, bc);
  transpose_w_k<<<dim3(20, 16), 256, 0, stream>>>(Wq, Wk, Wv, wt);
  gemm_qkv_k<<<dim3(512), 256, 0, stream>>>(xb, wt, bc, qk, vt);
  qks_k<<<dim3(1024), 512, 0, stream>>>(qk, Pm);
  pv_k<<<dim3(2048), 256, 0, stream>>>(Pm, vt, x, gm, out);
}